// Round 5
// baseline (2341.455 us; speedup 1.0000x reference)
//
#include <hip/hip_runtime.h>

#define BATCH 2048
#define CH 512            // conv batch-chunk size (4 chunks)

// ---------------------------------------------------------------------------
// Conv1: state [B,84,84,3] NHWC fp32 -> a1c [CH,32,20,20] NCHW fp32, 8x8 s4
// grid (CH, 10): (chunk image, group of 2 output rows). LDS 38.8 KB -> 4 blk/CU.
// ---------------------------------------------------------------------------
__global__ __launch_bounds__(256) void conv1_kernel(
    const float* __restrict__ state, const float* __restrict__ k1,
    const float* __restrict__ c1, float* __restrict__ a1c, int b0)
{
  __shared__ __align__(16) float wl2[192 * 36];   // row = c*64+ky*8+kx, col = oc
  __shared__ __align__(16) float il[3 * 12 * 84]; // planar [c][y(12)][x]
  const int bl  = blockIdx.x;
  const int b   = b0 + bl;
  const int oy0 = blockIdx.y * 2;      // output rows oy0, oy0+1
  const int t   = threadIdx.x;

  for (int i = t; i < 6144; i += 256) {
    int oc = i / 192, row = i % 192;
    wl2[row * 36 + oc] = k1[oc * 192 + row];
  }
  const float* sp = state + (size_t)b * (84 * 84 * 3) + (size_t)(oy0 * 4) * (84 * 3);
  for (int i = t; i < 12 * 84 * 3; i += 256) {   // 3024
    int c = i % 3, x = (i / 3) % 84, y = i / 252;
    il[(c * 12 + y) * 84 + x] = sp[i];
  }
  __syncthreads();

  const int ocg = (t & 7) * 4;        // 4 consecutive oc (of 32)
  const int oyl = (t >> 3) & 1;       // output row within pair
  const int oxg = t >> 4;             // 0..15 ; ox = oxg + j*16
  const int nox = (oxg < 4) ? 2 : 1;

  float acc[4][2] = {};
  for (int c = 0; c < 3; ++c) {
    for (int ky = 0; ky < 8; ++ky) {
      const float* irow = &il[(c * 12 + oyl * 4 + ky) * 84];
      float x[2][8];
      #pragma unroll
      for (int j = 0; j < 2; ++j) {
        if (j < nox) {
          const float4* ip = (const float4*)&irow[(oxg + j * 16) * 4];
          float4 x0 = ip[0], x1 = ip[1];
          x[j][0] = x0.x; x[j][1] = x0.y; x[j][2] = x0.z; x[j][3] = x0.w;
          x[j][4] = x1.x; x[j][5] = x1.y; x[j][6] = x1.z; x[j][7] = x1.w;
        }
      }
      #pragma unroll
      for (int kx = 0; kx < 8; ++kx) {
        const float4 wv = *(const float4*)&wl2[(c * 64 + ky * 8 + kx) * 36 + ocg];
        const float wa[4] = {wv.x, wv.y, wv.z, wv.w};
        #pragma unroll
        for (int j = 0; j < 2; ++j)
          if (j < nox)
            #pragma unroll
            for (int i = 0; i < 4; ++i)
              acc[i][j] += x[j][kx] * wa[i];
      }
    }
  }

  float* op = a1c + (size_t)bl * (32 * 400);
  for (int i = 0; i < 4; ++i) {
    float bias = c1[ocg + i];
    for (int j = 0; j < nox; ++j) {
      int ox = oxg + j * 16;
      op[((ocg + i) * 20 + (oy0 + oyl)) * 20 + ox] = fmaxf(acc[i][j] + bias, 0.f);
    }
  }
}

// ---------------------------------------------------------------------------
// Conv2: a1c [CH,32,20,20] -> a2c [CH,64,9,9], k 4x4 s2, relu.
// grid (CH, 2): (image, oc-half). LDS 31.2 KB -> 4 blk/CU at grid 1024.
// ---------------------------------------------------------------------------
__global__ __launch_bounds__(256) void conv2_kernel(
    const float* __restrict__ a1c, const float* __restrict__ k2,
    const float* __restrict__ c2, float* __restrict__ a2c)
{
  __shared__ __align__(16) float wl2[128 * 36];  // row = cc*16+ky*4+kx, 32 oc
  __shared__ __align__(16) float il[8 * 400];    // [cc][20][20]
  const int bl  = blockIdx.x;
  const int ocb = blockIdx.y;   // 0/1
  const int t   = threadIdx.x;
  const int oc0  = (t & 7) * 4; // within the 32-oc half
  const int pixg = t >> 3;      // 0..31; p = pixg + j*32, p < 81

  float acc[4][3] = {};
  for (int cb = 0; cb < 32; cb += 8) {
    __syncthreads();
    for (int i = t; i < 4096; i += 256) {
      int oc = i >> 7, r = i & 127;
      wl2[r * 36 + oc] = k2[(ocb * 32 + oc) * 512 + cb * 16 + r];
    }
    const float* ap = a1c + (size_t)bl * (32 * 400) + cb * 400;
    for (int i = t; i < 3200; i += 256) il[i] = ap[i];
    __syncthreads();

    for (int cc = 0; cc < 8; ++cc) {
      for (int ky = 0; ky < 4; ++ky) {
        float x[3][4];
        #pragma unroll
        for (int j = 0; j < 3; ++j) {
          int p = pixg + j * 32;
          if (p < 81) {
            int oyy = p / 9, oxx = p - oyy * 9;
            const float2* xp = (const float2*)&il[(cc * 20 + oyy * 2 + ky) * 20 + oxx * 2];
            float2 xa = xp[0], xb = xp[1];
            x[j][0] = xa.x; x[j][1] = xa.y; x[j][2] = xb.x; x[j][3] = xb.y;
          }
        }
        #pragma unroll
        for (int kx = 0; kx < 4; ++kx) {
          const float4 wv = *(const float4*)&wl2[(cc * 16 + ky * 4 + kx) * 36 + oc0];
          const float wa[4] = {wv.x, wv.y, wv.z, wv.w};
          #pragma unroll
          for (int j = 0; j < 3; ++j)
            if (pixg + j * 32 < 81)
              #pragma unroll
              for (int i = 0; i < 4; ++i)
                acc[i][j] += x[j][kx] * wa[i];
        }
      }
    }
  }

  float* op = a2c + (size_t)bl * (64 * 81);
  for (int i = 0; i < 4; ++i) {
    float bias = c2[ocb * 32 + oc0 + i];
    for (int j = 0; j < 3; ++j) {
      int p = pixg + j * 32;
      if (p < 81) op[(ocb * 32 + oc0 + i) * 81 + p] = fmaxf(acc[i][j] + bias, 0.f);
    }
  }
}

// ---------------------------------------------------------------------------
// Conv3: a2c [CH,64,9,9] -> a3 [B,3136] (NCHW flat), k 3x3 s1, relu.
// grid (CH, 2): (image, oc-half). LDS 13.8 KB.
// ---------------------------------------------------------------------------
__global__ __launch_bounds__(256) void conv3_kernel(
    const float* __restrict__ a2c, const float* __restrict__ k3,
    const float* __restrict__ c3, float* __restrict__ a3, int b0)
{
  __shared__ __align__(16) float wl2[72 * 36];   // row = cc*9+ky*3+kx, 32 oc
  __shared__ __align__(16) float il[8 * 9 * 12]; // [cc][9][x pad12]
  const int bl  = blockIdx.x;
  const int ocb = blockIdx.y;   // 0/1
  const int t   = threadIdx.x;
  const int oc0  = (t & 7) * 4;
  const int pixg = t >> 3;      // 0..31; p = pixg + j*32, p < 49

  float acc[4][2] = {};
  for (int cb = 0; cb < 64; cb += 8) {
    __syncthreads();
    for (int i = t; i < 2304; i += 256) {
      int oc = i / 72, row = i % 72;
      wl2[row * 36 + oc] = k3[(ocb * 32 + oc) * 576 + cb * 9 + row];
    }
    const float* ap = a2c + (size_t)bl * (64 * 81) + cb * 81;
    for (int i = t; i < 648; i += 256) {
      int cc = i / 81, r = i % 81, y = r / 9, xx = r - y * 9;
      il[(cc * 9 + y) * 12 + xx] = ap[i];
    }
    __syncthreads();

    for (int cc = 0; cc < 8; ++cc) {
      for (int ky = 0; ky < 3; ++ky) {
        float x[2][3];
        #pragma unroll
        for (int j = 0; j < 2; ++j) {
          int p = pixg + j * 32;
          if (p < 49) {
            int oyy = p / 7, oxx = p - oyy * 7;
            const float* ir = &il[(cc * 9 + oyy + ky) * 12 + oxx];
            x[j][0] = ir[0]; x[j][1] = ir[1]; x[j][2] = ir[2];
          }
        }
        #pragma unroll
        for (int kx = 0; kx < 3; ++kx) {
          const float4 wv = *(const float4*)&wl2[(cc * 9 + ky * 3 + kx) * 36 + oc0];
          const float wa[4] = {wv.x, wv.y, wv.z, wv.w};
          #pragma unroll
          for (int j = 0; j < 2; ++j)
            if (pixg + j * 32 < 49)
              #pragma unroll
              for (int i = 0; i < 4; ++i)
                acc[i][j] += x[j][kx] * wa[i];
        }
      }
    }
  }

  float* op = a3 + (size_t)(b0 + bl) * 3136;
  for (int i = 0; i < 4; ++i) {
    float bias = c3[ocb * 32 + oc0 + i];
    for (int j = 0; j < 2; ++j) {
      int p = pixg + j * 32;
      if (p < 49) op[(ocb * 32 + oc0 + i) * 49 + p] = fmaxf(acc[i][j] + bias, 0.f);
    }
  }
}

// ---------------------------------------------------------------------------
// Group samples by expert (single block, 1024 thr). Auto-detect i32/i64 rm.
// ---------------------------------------------------------------------------
__global__ void group_kernel(const void* __restrict__ rmv,
                             int* __restrict__ counts, int* __restrict__ idxb)
{
  __shared__ int isI32;
  const int t = threadIdx.x;
  if (t == 0) isI32 = 0;
  if (t < 8) counts[t] = 0;
  __syncthreads();
  unsigned long long v = ((const unsigned long long*)rmv)[t]; // first 8KB: safe either way
  if (v >= 8ull) isI32 = 1;
  __syncthreads();
  const int i32 = isI32;
  for (int b = t; b < BATCH; b += 1024) {
    int e = i32 ? ((const int*)rmv)[b] : (int)((const long long*)rmv)[b];
    int pos = atomicAdd(&counts[e], 1);
    idxb[e * BATCH + pos] = b;
  }
}

// ---------------------------------------------------------------------------
// GEMM1 (grouped): H1[s][64] += a3[s][k] * W1[e][k][64] over K-slice 448, only
// for samples s routed to expert e. grid (8*32, 7), empty tiles exit.
// ---------------------------------------------------------------------------
__global__ __launch_bounds__(256) void gemm1_grp_kernel(
    const float* __restrict__ a3, const int* __restrict__ counts,
    const int* __restrict__ idxb, const float* __restrict__ W1,
    float* __restrict__ H1)
{
  __shared__ __align__(16) float At[32 * 68]; // [kk][r pad68]
  __shared__ __align__(16) float Bw[32 * 64]; // [kk][h]
  __shared__ int s_id[64];
  const int e  = blockIdx.x >> 5;
  const int tl = blockIdx.x & 31;
  const int ks = blockIdx.y;
  const int cnt = counts[e];
  const int n0 = tl * 64;
  if (n0 >= cnt) return;
  const int m = min(64, cnt - n0);
  const int t = threadIdx.x;
  if (t < 64) s_id[t] = idxb[e * BATCH + n0 + min(t, m - 1)];
  __syncthreads();

  const int tx = t & 15, ty = t >> 4;
  const int c0 = tx * 4, r0 = ty * 4;
  const float* W1e = W1 + (size_t)e * 3136 * 64;
  float acc[4][4] = {};
  const int kbase = ks * 448;

  for (int k0 = kbase; k0 < kbase + 448; k0 += 32) {
    __syncthreads();
    {
      int i = t;
      #pragma unroll
      for (int pass = 0; pass < 2; ++pass, i += 256) {
        int r = i >> 3, k4 = (i & 7) * 4;
        float4 v = *(const float4*)(a3 + (size_t)s_id[r] * 3136 + k0 + k4);
        At[(k4 + 0) * 68 + r] = v.x; At[(k4 + 1) * 68 + r] = v.y;
        At[(k4 + 2) * 68 + r] = v.z; At[(k4 + 3) * 68 + r] = v.w;
      }
      int i2 = t;
      #pragma unroll
      for (int pass = 0; pass < 2; ++pass, i2 += 256) {
        int kk = i2 >> 4, h4 = (i2 & 15) * 4;
        *(float4*)&Bw[kk * 64 + h4] = *(const float4*)&W1e[(size_t)(k0 + kk) * 64 + h4];
      }
    }
    __syncthreads();
    #pragma unroll
    for (int kk = 0; kk < 32; ++kk) {
      float4 a = *(const float4*)&At[kk * 68 + r0];
      float4 bb = *(const float4*)&Bw[kk * 64 + c0];
      float av[4] = {a.x, a.y, a.z, a.w}, bv[4] = {bb.x, bb.y, bb.z, bb.w};
      #pragma unroll
      for (int ii = 0; ii < 4; ++ii)
        #pragma unroll
        for (int j = 0; j < 4; ++j)
          acc[ii][j] += av[ii] * bv[j];
    }
  }

  #pragma unroll
  for (int ii = 0; ii < 4; ++ii) {
    if (r0 + ii < m) {
      int s = s_id[r0 + ii];
      #pragma unroll
      for (int j = 0; j < 4; ++j)
        atomicAdd(&H1[(size_t)s * 64 + c0 + j], acc[ii][j]);
    }
  }
}

// ---------------------------------------------------------------------------
// MLP tail (grouped): bias+relu H1, layers 2..5, layer 6, scatter to out.
// grid (8*32), empty tiles exit. W6l staged with strided loop (r4 bugfix).
// ---------------------------------------------------------------------------
__global__ __launch_bounds__(256) void tail_grp_kernel(
    const float* __restrict__ H1, const int* __restrict__ counts,
    const int* __restrict__ idxb, const float* __restrict__ B1,
    const float* __restrict__ W2, const float* __restrict__ B2,
    const float* __restrict__ W3, const float* __restrict__ B3,
    const float* __restrict__ W4, const float* __restrict__ B4,
    const float* __restrict__ W5, const float* __restrict__ B5,
    const float* __restrict__ W6, const float* __restrict__ B6,
    float* __restrict__ out)
{
  __shared__ __align__(16) float Wl[4096];
  __shared__ float bl[64];
  __shared__ float W6l[384];
  __shared__ float B6l[8];
  __shared__ __align__(16) float Ht0[64 * 68]; // [c][r]
  __shared__ __align__(16) float Ht1[64 * 68];
  __shared__ int s_id[64];

  const int e  = blockIdx.x >> 5;
  const int tl = blockIdx.x & 31;
  const int cnt = counts[e];
  const int n0 = tl * 64;
  if (n0 >= cnt) return;
  const int m = min(64, cnt - n0);
  const int t = threadIdx.x;
  if (t < 64) s_id[t] = idxb[e * BATCH + n0 + min(t, m - 1)];
  for (int i = t; i < 384; i += 256) W6l[i] = W6[e * 384 + i];
  if (t < 6)   B6l[t] = B6[e * 6 + t];
  __syncthreads();

  #pragma unroll
  for (int p = 0; p < 16; ++p) {
    int i = t + p * 256;
    int c = i & 63, r = i >> 6;
    Ht0[c * 68 + r] = fmaxf(H1[(size_t)s_id[r] * 64 + c] + B1[e * 64 + c], 0.f);
  }

  const int tx = t & 15, ty = t >> 4;
  const int c0 = tx * 4, r0 = ty * 4;
  const float* Ws[4] = {W2, W3, W4, W5};
  const float* Bs[4] = {B2, B3, B4, B5};
  float* Hc = Ht0; float* Hn = Ht1;

  for (int L = 0; L < 4; ++L) {
    __syncthreads();
    const float* We = Ws[L] + (size_t)e * 4096;
    for (int i = t; i < 1024; i += 256)
      *(float4*)&Wl[i * 4] = *(const float4*)&We[i * 4];
    if (t < 64) bl[t] = Bs[L][e * 64 + t];
    __syncthreads();

    float acc[4][4] = {};
    #pragma unroll 4
    for (int kk = 0; kk < 64; ++kk) {
      float4 a = *(const float4*)&Hc[kk * 68 + r0];
      float4 bb = *(const float4*)&Wl[kk * 64 + c0];
      float av[4] = {a.x, a.y, a.z, a.w}, bv[4] = {bb.x, bb.y, bb.z, bb.w};
      #pragma unroll
      for (int ii = 0; ii < 4; ++ii)
        #pragma unroll
        for (int j = 0; j < 4; ++j)
          acc[ii][j] += av[ii] * bv[j];
    }
    __syncthreads();
    #pragma unroll
    for (int j = 0; j < 4; ++j) {
      float bias = bl[c0 + j];
      #pragma unroll
      for (int ii = 0; ii < 4; ++ii)
        Hn[(c0 + j) * 68 + r0 + ii] = fmaxf(acc[ii][j] + bias, 0.f);
    }
    float* tmp = Hc; Hc = Hn; Hn = tmp;
  }
  __syncthreads();

  const int r = t & 63, aa = t >> 6;
  float s0v = 0.f, s1v = 0.f;
  for (int k = 0; k < 64; ++k) {
    float h = Hc[k * 68 + r];
    s0v += h * W6l[k * 6 + aa];
    s1v += h * W6l[k * 6 + ((aa < 2) ? aa + 4 : aa)];
  }
  if (r < m) {
    int s = s_id[r];
    out[s * 6 + aa] = s0v + B6l[aa];
    if (aa < 2) out[s * 6 + aa + 4] = s1v + B6l[aa + 4];
  }
}

// ---------------------------------------------------------------------------
extern "C" void kernel_launch(void* const* d_in, const int* in_sizes, int n_in,
                              void* d_out, int out_size, void* d_ws, size_t ws_size,
                              hipStream_t stream) {
  const float* state = (const float*)d_in[0];
  const void*  rm    = d_in[1];
  const float* k1 = (const float*)d_in[2];
  const float* c1 = (const float*)d_in[3];
  const float* k2 = (const float*)d_in[4];
  const float* c2 = (const float*)d_in[5];
  const float* k3 = (const float*)d_in[6];
  const float* c3 = (const float*)d_in[7];
  const float* W1 = (const float*)d_in[8];
  const float* B1 = (const float*)d_in[9];
  const float* W2 = (const float*)d_in[10];
  const float* B2 = (const float*)d_in[11];
  const float* W3 = (const float*)d_in[12];
  const float* B3 = (const float*)d_in[13];
  const float* W4 = (const float*)d_in[14];
  const float* B4 = (const float*)d_in[15];
  const float* W5 = (const float*)d_in[16];
  const float* B5 = (const float*)d_in[17];
  const float* W6 = (const float*)d_in[18];
  const float* B6 = (const float*)d_in[19];

  // workspace layout (~63.1 MB, known-safe budget), all internal buffers fp32
  char* ws = (char*)d_ws;
  float* a3   = (float*)(ws);                  // 2048*3136*4 = 25,690,112
  float* H1   = (float*)(ws + 25690112);       // 2048*64*4   =     524,288
  int* counts = (int*)  (ws + 26214400);       // 8*4
  int* idxb   = (int*)  (ws + 26214432);       // 8*2048*4    =      65,536
  float* a1c  = (float*)(ws + 26280064);       // 512*12800*4 =  26,214,400
  float* a2c  = (float*)(ws + 52494464);       // 512*5184*4  =  10,616,832
                                               // end: 63,111,296

  hipMemsetAsync(H1, 0, BATCH * 64 * sizeof(float), stream);
  group_kernel<<<1, 1024, 0, stream>>>(rm, counts, idxb);

  for (int b0 = 0; b0 < BATCH; b0 += CH) {
    conv1_kernel<<<dim3(CH, 10), 256, 0, stream>>>(state, k1, c1, a1c, b0);
    conv2_kernel<<<dim3(CH, 2), 256, 0, stream>>>(a1c, k2, c2, a2c);
    conv3_kernel<<<dim3(CH, 2), 256, 0, stream>>>(a2c, k3, c3, a3, b0);
  }

  gemm1_grp_kernel<<<dim3(256, 7), 256, 0, stream>>>(a3, counts, idxb, W1, H1);
  tail_grp_kernel<<<256, 256, 0, stream>>>(H1, counts, idxb, B1,
                                           W2, B2, W3, B3, W4, B4, W5, B5,
                                           W6, B6, (float*)d_out);
}

// Round 6
// 868.803 us; speedup vs baseline: 2.6950x; 2.6950x over previous
//
#include <hip/hip_runtime.h>

#define BATCH 2048
#define CH 512            // conv batch-chunk size (4 chunks)

typedef unsigned short u16;
typedef __attribute__((ext_vector_type(8))) short bf16x8;  // 8 bf16 = 4 VGPR
typedef __attribute__((ext_vector_type(4))) float f32x4;   // MFMA 16x16 acc

static __device__ __forceinline__ float b2f(u16 h) {
  union { unsigned u; float f; } x; x.u = ((unsigned)h) << 16; return x.f;
}
static __device__ __forceinline__ u16 f2b(float f) {  // RNE fp32->bf16
  union { float f; unsigned u; } x; x.f = f;
  return (u16)((x.u + 0x7fffu + ((x.u >> 16) & 1u)) >> 16);
}
static __device__ __forceinline__ void split2(float v, u16& h, u16& l) {
  h = f2b(v); l = f2b(v - b2f(h));
}

// ---------------------------------------------------------------------------
// Pre-split conv weights to bf16 hi/lo, swizzled [chunk][oc][kk(32)] so B-frag
// loads are contiguous ds_read_b128. W1s: [2][6][32][32], W2s: [2][16][64][32],
// W3s: [2][18][64][32]. 75776 threads total (grid 296 x 256).
// ---------------------------------------------------------------------------
__global__ void wsplit_kernel(const float* __restrict__ k1,
                              const float* __restrict__ k2,
                              const float* __restrict__ k3,
                              u16* __restrict__ W1s, u16* __restrict__ W2s,
                              u16* __restrict__ W3s)
{
  int id = blockIdx.x * 256 + threadIdx.x;   // 0..75775
  float v; u16 *dh, *dl;
  if (id < 6144) {
    int oc = (id >> 5) & 31, kk = id & 31, chunk = id >> 10;
    v = k1[oc * 192 + chunk * 32 + kk];
    dh = W1s + id; dl = W1s + 6144 + id;
  } else if (id < 38912) {
    int i2 = id - 6144;
    int oc = (i2 >> 5) & 63, kk = i2 & 31, chunk = i2 >> 11;
    v = k2[oc * 512 + chunk * 32 + kk];
    dh = W2s + i2; dl = W2s + 32768 + i2;
  } else {
    int i3 = id - 38912;
    int oc = (i3 >> 5) & 63, kk = i3 & 31, chunk = i3 >> 11;
    v = k3[oc * 576 + chunk * 32 + kk];
    dh = W3s + i3; dl = W3s + 36864 + i3;
  }
  u16 h, l; split2(v, h, l); *dh = h; *dl = l;
}

// ---------------------------------------------------------------------------
// Conv1 MFMA: state [B,84,84,3] NHWC fp32 -> a1c [CH,32,20,20] fp32, 8x8 s4.
// grid (CH, 5): (image, 4-out-row band = 80 px). 128 thr = 2 waves (oc-tiles).
// K=192 (6 chunks); im2col A built in LDS per chunk (hi+lo).
// ---------------------------------------------------------------------------
__global__ __launch_bounds__(128) void conv1_kernel(
    const float* __restrict__ state, const u16* __restrict__ W1s,
    const float* __restrict__ c1, float* __restrict__ a1c, int b0)
{
  __shared__ float il[3 * 20 * 84];             // planar [c][20 rows][84]
  __shared__ u16 Ah[5 * 512], Al[5 * 512];      // [px-tile][16 px][32 k]
  __shared__ u16 Bh[1024], Bl[1024];            // [32 oc][32 k]
  const int bl = blockIdx.x, by = blockIdx.y, t = threadIdx.x;
  const int b = b0 + bl;

  const float* sp = state + (size_t)b * (84 * 84 * 3) + (size_t)(by * 16) * 252;
  for (int i = t; i < 5040; i += 128) {         // 20 rows, NHWC -> planar
    int c = i % 3, x = (i / 3) % 84, y = i / 252;
    il[(c * 20 + y) * 84 + x] = sp[i];
  }

  const int lane = t & 63, w = t >> 6, q = lane >> 4, n = lane & 15;
  f32x4 acc[5] = {};

  for (int ch = 0; ch < 6; ++ch) {
    __syncthreads();
    ((float4*)Bh)[t & 127] = ((const float4*)(W1s + ch * 1024))[t & 127];
    ((float4*)Bl)[t & 127] = ((const float4*)(W1s + 6144 + ch * 1024))[t & 127];
    for (int e = t; e < 2560; e += 128) {
      int px = e >> 5, kk = e & 31;             // px = tile*16+pxl directly
      int k = ch * 32 + kk;
      int c = k >> 6, ky = (k >> 3) & 7, kx = k & 7;
      int py = (px * 205) >> 12, pxx = px - py * 20;
      float v = il[(c * 20 + py * 4 + ky) * 84 + pxx * 4 + kx];
      u16 h, l; split2(v, h, l);
      Ah[e] = h; Al[e] = l;
    }
    __syncthreads();
    bf16x8 bh = *(const bf16x8*)&Bh[(w * 16 + n) * 32 + q * 8];
    bf16x8 bo = *(const bf16x8*)&Bl[(w * 16 + n) * 32 + q * 8];
    #pragma unroll
    for (int pt = 0; pt < 5; ++pt) {
      bf16x8 ah = *(const bf16x8*)&Ah[pt * 512 + n * 32 + q * 8];
      bf16x8 al = *(const bf16x8*)&Al[pt * 512 + n * 32 + q * 8];
      acc[pt] = __builtin_amdgcn_mfma_f32_16x16x32_bf16(ah, bh, acc[pt], 0, 0, 0);
      acc[pt] = __builtin_amdgcn_mfma_f32_16x16x32_bf16(ah, bo, acc[pt], 0, 0, 0);
      acc[pt] = __builtin_amdgcn_mfma_f32_16x16x32_bf16(al, bh, acc[pt], 0, 0, 0);
    }
  }

  const int oc = w * 16 + n;
  const float bias = c1[oc];
  float* op = a1c + (size_t)bl * 12800 + oc * 400;
  #pragma unroll
  for (int pt = 0; pt < 5; ++pt)
    #pragma unroll
    for (int r = 0; r < 4; ++r) {
      int pxl = pt * 16 + q * 4 + r;
      int py = (pxl * 205) >> 12, pxx = pxl - py * 20;
      op[(by * 4 + py) * 20 + pxx] = fmaxf(acc[pt][r] + bias, 0.f);
    }
}

// ---------------------------------------------------------------------------
// Conv2 MFMA: a1c [CH,32,20,20] -> a2c [CH,64,9,9], 4x4 s2. grid (CH).
// 256 thr = 4 waves (oc-tiles). K=512 (16 chunks), 6 px-tiles (96 >= 81).
// ---------------------------------------------------------------------------
__global__ __launch_bounds__(256) void conv2_kernel(
    const float* __restrict__ a1c, const u16* __restrict__ W2s,
    const float* __restrict__ c2, float* __restrict__ a2c)
{
  __shared__ float il[32 * 400];                // 51.2 KB
  __shared__ u16 Ah[6 * 512], Al[6 * 512];
  __shared__ u16 Bh[2048], Bl[2048];            // [64 oc][32 k]
  const int bl = blockIdx.x, t = threadIdx.x;

  const float* ap = a1c + (size_t)bl * 12800;
  for (int i = t; i < 3200; i += 256)
    ((float4*)il)[i] = ((const float4*)ap)[i];

  const int lane = t & 63, w = t >> 6, q = lane >> 4, n = lane & 15;
  f32x4 acc[6] = {};

  for (int ch = 0; ch < 16; ++ch) {
    __syncthreads();
    ((float4*)Bh)[t] = ((const float4*)(W2s + ch * 2048))[t];
    ((float4*)Bl)[t] = ((const float4*)(W2s + 32768 + ch * 2048))[t];
    for (int e = t; e < 3072; e += 256) {
      int px = e >> 5, kk = e & 31;
      u16 h = 0, l = 0;
      if (px < 81) {
        int k = ch * 32 + kk;
        int cc = k >> 4, ky = (k >> 2) & 3, kx = k & 3;
        int py = (px * 7282) >> 16, pxx = px - py * 9;
        float v = il[cc * 400 + (py * 2 + ky) * 20 + pxx * 2 + kx];
        split2(v, h, l);
      }
      Ah[e] = h; Al[e] = l;
    }
    __syncthreads();
    bf16x8 bh = *(const bf16x8*)&Bh[(w * 16 + n) * 32 + q * 8];
    bf16x8 bo = *(const bf16x8*)&Bl[(w * 16 + n) * 32 + q * 8];
    #pragma unroll
    for (int pt = 0; pt < 6; ++pt) {
      bf16x8 ah = *(const bf16x8*)&Ah[pt * 512 + n * 32 + q * 8];
      bf16x8 al = *(const bf16x8*)&Al[pt * 512 + n * 32 + q * 8];
      acc[pt] = __builtin_amdgcn_mfma_f32_16x16x32_bf16(ah, bh, acc[pt], 0, 0, 0);
      acc[pt] = __builtin_amdgcn_mfma_f32_16x16x32_bf16(ah, bo, acc[pt], 0, 0, 0);
      acc[pt] = __builtin_amdgcn_mfma_f32_16x16x32_bf16(al, bh, acc[pt], 0, 0, 0);
    }
  }

  const int oc = w * 16 + n;
  const float bias = c2[oc];
  float* op = a2c + (size_t)bl * 5184 + oc * 81;
  #pragma unroll
  for (int pt = 0; pt < 6; ++pt)
    #pragma unroll
    for (int r = 0; r < 4; ++r) {
      int px = pt * 16 + q * 4 + r;
      if (px < 81) op[px] = fmaxf(acc[pt][r] + bias, 0.f);
    }
}

// ---------------------------------------------------------------------------
// Conv3 MFMA: a2c [CH,64,9,9] -> a3 [B,3136], 3x3 s1. grid (CH).
// 256 thr = 4 waves. K=576 (18 chunks), 4 px-tiles (64 >= 49).
// ---------------------------------------------------------------------------
__global__ __launch_bounds__(256) void conv3_kernel(
    const float* __restrict__ a2c, const u16* __restrict__ W3s,
    const float* __restrict__ c3, float* __restrict__ a3, int b0)
{
  __shared__ float il[64 * 81];                 // 20.7 KB
  __shared__ u16 Ah[4 * 512], Al[4 * 512];
  __shared__ u16 Bh[2048], Bl[2048];
  const int bl = blockIdx.x, t = threadIdx.x;

  const float* ap = a2c + (size_t)bl * 5184;
  for (int i = t; i < 1296; i += 256)
    ((float4*)il)[i] = ((const float4*)ap)[i];

  const int lane = t & 63, w = t >> 6, q = lane >> 4, n = lane & 15;
  f32x4 acc[4] = {};

  for (int ch = 0; ch < 18; ++ch) {
    __syncthreads();
    ((float4*)Bh)[t] = ((const float4*)(W3s + ch * 2048))[t];
    ((float4*)Bl)[t] = ((const float4*)(W3s + 36864 + ch * 2048))[t];
    for (int e = t; e < 2048; e += 256) {
      int px = e >> 5, kk = e & 31;
      u16 h = 0, l = 0;
      if (px < 49) {
        int k = ch * 32 + kk;
        int cc = (k * 7282) >> 16;              // /9 for k<576
        int r9 = k - cc * 9;
        int ky = (r9 * 11) >> 5, kx = r9 - ky * 3;
        int py = (px * 74) >> 9, pxx = px - py * 7;   // /7 for px<49
        float v = il[cc * 81 + (py + ky) * 9 + pxx + kx];
        split2(v, h, l);
      }
      Ah[e] = h; Al[e] = l;
    }
    __syncthreads();
    bf16x8 bh = *(const bf16x8*)&Bh[(w * 16 + n) * 32 + q * 8];
    bf16x8 bo = *(const bf16x8*)&Bl[(w * 16 + n) * 32 + q * 8];
    #pragma unroll
    for (int pt = 0; pt < 4; ++pt) {
      bf16x8 ah = *(const bf16x8*)&Ah[pt * 512 + n * 32 + q * 8];
      bf16x8 al = *(const bf16x8*)&Al[pt * 512 + n * 32 + q * 8];
      acc[pt] = __builtin_amdgcn_mfma_f32_16x16x32_bf16(ah, bh, acc[pt], 0, 0, 0);
      acc[pt] = __builtin_amdgcn_mfma_f32_16x16x32_bf16(ah, bo, acc[pt], 0, 0, 0);
      acc[pt] = __builtin_amdgcn_mfma_f32_16x16x32_bf16(al, bh, acc[pt], 0, 0, 0);
    }
  }

  const int oc = w * 16 + n;
  const float bias = c3[oc];
  float* op = a3 + (size_t)(b0 + bl) * 3136 + oc * 49;
  #pragma unroll
  for (int pt = 0; pt < 4; ++pt)
    #pragma unroll
    for (int r = 0; r < 4; ++r) {
      int px = pt * 16 + q * 4 + r;
      if (px < 49) op[px] = fmaxf(acc[pt][r] + bias, 0.f);
    }
}

// ---------------------------------------------------------------------------
// Group samples by expert (single block, 1024 thr). Auto-detect i32/i64 rm.
// ---------------------------------------------------------------------------
__global__ void group_kernel(const void* __restrict__ rmv,
                             int* __restrict__ counts, int* __restrict__ idxb)
{
  __shared__ int isI32;
  const int t = threadIdx.x;
  if (t == 0) isI32 = 0;
  if (t < 8) counts[t] = 0;
  __syncthreads();
  unsigned long long v = ((const unsigned long long*)rmv)[t];
  if (v >= 8ull) isI32 = 1;
  __syncthreads();
  const int i32 = isI32;
  for (int b = t; b < BATCH; b += 1024) {
    int e = i32 ? ((const int*)rmv)[b] : (int)((const long long*)rmv)[b];
    int pos = atomicAdd(&counts[e], 1);
    idxb[e * BATCH + pos] = b;
  }
}

// ---------------------------------------------------------------------------
// GEMM1 (grouped, fp32): H1[s][64] += a3[s][k]*W1[e][k][64], K-split 7x448.
// ---------------------------------------------------------------------------
__global__ __launch_bounds__(256) void gemm1_grp_kernel(
    const float* __restrict__ a3, const int* __restrict__ counts,
    const int* __restrict__ idxb, const float* __restrict__ W1,
    float* __restrict__ H1)
{
  __shared__ __align__(16) float At[32 * 68];
  __shared__ __align__(16) float Bw[32 * 64];
  __shared__ int s_id[64];
  const int e  = blockIdx.x >> 5;
  const int tl = blockIdx.x & 31;
  const int ks = blockIdx.y;
  const int cnt = counts[e];
  const int n0 = tl * 64;
  if (n0 >= cnt) return;
  const int m = min(64, cnt - n0);
  const int t = threadIdx.x;
  if (t < 64) s_id[t] = idxb[e * BATCH + n0 + min(t, m - 1)];
  __syncthreads();

  const int tx = t & 15, ty = t >> 4;
  const int c0 = tx * 4, r0 = ty * 4;
  const float* W1e = W1 + (size_t)e * 3136 * 64;
  float acc[4][4] = {};
  const int kbase = ks * 448;

  for (int k0 = kbase; k0 < kbase + 448; k0 += 32) {
    __syncthreads();
    {
      int i = t;
      #pragma unroll
      for (int pass = 0; pass < 2; ++pass, i += 256) {
        int r = i >> 3, k4 = (i & 7) * 4;
        float4 v = *(const float4*)(a3 + (size_t)s_id[r] * 3136 + k0 + k4);
        At[(k4 + 0) * 68 + r] = v.x; At[(k4 + 1) * 68 + r] = v.y;
        At[(k4 + 2) * 68 + r] = v.z; At[(k4 + 3) * 68 + r] = v.w;
      }
      int i2 = t;
      #pragma unroll
      for (int pass = 0; pass < 2; ++pass, i2 += 256) {
        int kk = i2 >> 4, h4 = (i2 & 15) * 4;
        *(float4*)&Bw[kk * 64 + h4] = *(const float4*)&W1e[(size_t)(k0 + kk) * 64 + h4];
      }
    }
    __syncthreads();
    #pragma unroll
    for (int kk = 0; kk < 32; ++kk) {
      float4 a = *(const float4*)&At[kk * 68 + r0];
      float4 bb = *(const float4*)&Bw[kk * 64 + c0];
      float av[4] = {a.x, a.y, a.z, a.w}, bv[4] = {bb.x, bb.y, bb.z, bb.w};
      #pragma unroll
      for (int ii = 0; ii < 4; ++ii)
        #pragma unroll
        for (int j = 0; j < 4; ++j)
          acc[ii][j] += av[ii] * bv[j];
    }
  }

  #pragma unroll
  for (int ii = 0; ii < 4; ++ii) {
    if (r0 + ii < m) {
      int s = s_id[r0 + ii];
      #pragma unroll
      for (int j = 0; j < 4; ++j)
        atomicAdd(&H1[(size_t)s * 64 + c0 + j], acc[ii][j]);
    }
  }
}

// ---------------------------------------------------------------------------
// MLP tail (grouped): bias+relu H1, layers 2..5, layer 6, scatter to out.
// ---------------------------------------------------------------------------
__global__ __launch_bounds__(256) void tail_grp_kernel(
    const float* __restrict__ H1, const int* __restrict__ counts,
    const int* __restrict__ idxb, const float* __restrict__ B1,
    const float* __restrict__ W2, const float* __restrict__ B2,
    const float* __restrict__ W3, const float* __restrict__ B3,
    const float* __restrict__ W4, const float* __restrict__ B4,
    const float* __restrict__ W5, const float* __restrict__ B5,
    const float* __restrict__ W6, const float* __restrict__ B6,
    float* __restrict__ out)
{
  __shared__ __align__(16) float Wl[4096];
  __shared__ float bl[64];
  __shared__ float W6l[384];
  __shared__ float B6l[8];
  __shared__ __align__(16) float Ht0[64 * 68];
  __shared__ __align__(16) float Ht1[64 * 68];
  __shared__ int s_id[64];

  const int e  = blockIdx.x >> 5;
  const int tl = blockIdx.x & 31;
  const int cnt = counts[e];
  const int n0 = tl * 64;
  if (n0 >= cnt) return;
  const int m = min(64, cnt - n0);
  const int t = threadIdx.x;
  if (t < 64) s_id[t] = idxb[e * BATCH + n0 + min(t, m - 1)];
  for (int i = t; i < 384; i += 256) W6l[i] = W6[e * 384 + i];
  if (t < 6)   B6l[t] = B6[e * 6 + t];
  __syncthreads();

  #pragma unroll
  for (int p = 0; p < 16; ++p) {
    int i = t + p * 256;
    int c = i & 63, r = i >> 6;
    Ht0[c * 68 + r] = fmaxf(H1[(size_t)s_id[r] * 64 + c] + B1[e * 64 + c], 0.f);
  }

  const int tx = t & 15, ty = t >> 4;
  const int c0 = tx * 4, r0 = ty * 4;
  const float* Ws[4] = {W2, W3, W4, W5};
  const float* Bs[4] = {B2, B3, B4, B5};
  float* Hc = Ht0; float* Hn = Ht1;

  for (int L = 0; L < 4; ++L) {
    __syncthreads();
    const float* We = Ws[L] + (size_t)e * 4096;
    for (int i = t; i < 1024; i += 256)
      *(float4*)&Wl[i * 4] = *(const float4*)&We[i * 4];
    if (t < 64) bl[t] = Bs[L][e * 64 + t];
    __syncthreads();

    float acc[4][4] = {};
    #pragma unroll 4
    for (int kk = 0; kk < 64; ++kk) {
      float4 a = *(const float4*)&Hc[kk * 68 + r0];
      float4 bb = *(const float4*)&Wl[kk * 64 + c0];
      float av[4] = {a.x, a.y, a.z, a.w}, bv[4] = {bb.x, bb.y, bb.z, bb.w};
      #pragma unroll
      for (int ii = 0; ii < 4; ++ii)
        #pragma unroll
        for (int j = 0; j < 4; ++j)
          acc[ii][j] += av[ii] * bv[j];
    }
    __syncthreads();
    #pragma unroll
    for (int j = 0; j < 4; ++j) {
      float bias = bl[c0 + j];
      #pragma unroll
      for (int ii = 0; ii < 4; ++ii)
        Hn[(c0 + j) * 68 + r0 + ii] = fmaxf(acc[ii][j] + bias, 0.f);
    }
    float* tmp = Hc; Hc = Hn; Hn = tmp;
  }
  __syncthreads();

  const int r = t & 63, aa = t >> 6;
  float s0v = 0.f, s1v = 0.f;
  for (int k = 0; k < 64; ++k) {
    float h = Hc[k * 68 + r];
    s0v += h * W6l[k * 6 + aa];
    s1v += h * W6l[k * 6 + ((aa < 2) ? aa + 4 : aa)];
  }
  if (r < m) {
    int s = s_id[r];
    out[s * 6 + aa] = s0v + B6l[aa];
    if (aa < 2) out[s * 6 + aa + 4] = s1v + B6l[aa + 4];
  }
}

// ---------------------------------------------------------------------------
extern "C" void kernel_launch(void* const* d_in, const int* in_sizes, int n_in,
                              void* d_out, int out_size, void* d_ws, size_t ws_size,
                              hipStream_t stream) {
  const float* state = (const float*)d_in[0];
  const void*  rm    = d_in[1];
  const float* k1 = (const float*)d_in[2];
  const float* c1 = (const float*)d_in[3];
  const float* k2 = (const float*)d_in[4];
  const float* c2 = (const float*)d_in[5];
  const float* k3 = (const float*)d_in[6];
  const float* c3 = (const float*)d_in[7];
  const float* W1 = (const float*)d_in[8];
  const float* B1 = (const float*)d_in[9];
  const float* W2 = (const float*)d_in[10];
  const float* B2 = (const float*)d_in[11];
  const float* W3 = (const float*)d_in[12];
  const float* B3 = (const float*)d_in[13];
  const float* W4 = (const float*)d_in[14];
  const float* B4 = (const float*)d_in[15];
  const float* W5 = (const float*)d_in[16];
  const float* B5 = (const float*)d_in[17];
  const float* W6 = (const float*)d_in[18];
  const float* B6 = (const float*)d_in[19];

  // workspace layout (~63.4 MB; <= 66.7 MB proven-safe)
  char* ws = (char*)d_ws;
  float* a3   = (float*)(ws);                  // 25,690,112
  float* H1   = (float*)(ws + 25690112);       //    524,288
  int* counts = (int*)  (ws + 26214400);       //         32
  int* idxb   = (int*)  (ws + 26214432);       //     65,536 (+pad)
  float* a1c  = (float*)(ws + 26280064);       // 26,214,400
  float* a2c  = (float*)(ws + 52494464);       // 10,616,832
  u16* W1s    = (u16*)  (ws + 63111296);       //     24,576
  u16* W2s    = (u16*)  (ws + 63135872);       //    131,072
  u16* W3s    = (u16*)  (ws + 63266944);       //    147,456 -> end 63,414,400

  wsplit_kernel<<<296, 256, 0, stream>>>(k1, k2, k3, W1s, W2s, W3s);
  hipMemsetAsync(H1, 0, BATCH * 64 * sizeof(float), stream);
  group_kernel<<<1, 1024, 0, stream>>>(rm, counts, idxb);

  for (int b0 = 0; b0 < BATCH; b0 += CH) {
    conv1_kernel<<<dim3(CH, 5), 128, 0, stream>>>(state, W1s, c1, a1c, b0);
    conv2_kernel<<<CH, 256, 0, stream>>>(a1c, W2s, c2, a2c);
    conv3_kernel<<<CH, 256, 0, stream>>>(a2c, W3s, c3, a3, b0);
  }

  gemm1_grp_kernel<<<dim3(256, 7), 256, 0, stream>>>(a3, counts, idxb, W1, H1);
  tail_grp_kernel<<<256, 256, 0, stream>>>(H1, counts, idxb, B1,
                                           W2, B2, W3, B3, W4, B4, W5, B5,
                                           W6, B6, (float*)d_out);
}